// Round 1
// baseline (887.827 us; speedup 1.0000x reference)
//
#include <hip/hip_runtime.h>

#define F_IN 512
#define F_HID 16
#define F_OUT 7

// ---------------- degree ----------------
__global__ void k_init_deg(float* __restrict__ deg, int n) {
    int i = blockIdx.x * blockDim.x + threadIdx.x;
    if (i < n) deg[i] = 1.0f;   // self-loop contribution
}

__global__ void k_deg(const int* __restrict__ dst, float* __restrict__ deg, int E) {
    int e = blockIdx.x * blockDim.x + threadIdx.x;
    if (e < E) atomicAdd(&deg[dst[e]], 1.0f);
}

// ---------------- GEMM1: h1 = x @ W1  (one row per thread) ----------------
__global__ void k_gemm1(const float* __restrict__ x, const float* __restrict__ W,
                        float* __restrict__ h1, int n) {
    int r = blockIdx.x * blockDim.x + threadIdx.x;
    if (r >= n) return;
    float acc[F_HID];
#pragma unroll
    for (int c = 0; c < F_HID; ++c) acc[c] = 0.0f;
    const float4* xr = (const float4*)(x + (size_t)r * F_IN);
    for (int k4 = 0; k4 < F_IN / 4; ++k4) {
        float4 xv = xr[k4];
        int k = k4 * 4;
#pragma unroll
        for (int c = 0; c < F_HID; ++c) {
            // W index is wave-uniform (k uniform, c unrolled const) -> s_load path
            acc[c] = fmaf(xv.x, W[(k + 0) * F_HID + c], acc[c]);
            acc[c] = fmaf(xv.y, W[(k + 1) * F_HID + c], acc[c]);
            acc[c] = fmaf(xv.z, W[(k + 2) * F_HID + c], acc[c]);
            acc[c] = fmaf(xv.w, W[(k + 3) * F_HID + c], acc[c]);
        }
    }
    float4* o = (float4*)(h1 + (size_t)r * F_HID);
    o[0] = make_float4(acc[0], acc[1], acc[2], acc[3]);
    o[1] = make_float4(acc[4], acc[5], acc[6], acc[7]);
    o[2] = make_float4(acc[8], acc[9], acc[10], acc[11]);
    o[3] = make_float4(acc[12], acc[13], acc[14], acc[15]);
}

// ---------------- dinv + self-loop init of agg1 (also zero-fills) ----------------
__global__ void k_dinv_self1(const float* __restrict__ deg, float* __restrict__ dinv,
                             const float* __restrict__ h1, float* __restrict__ agg1, int n) {
    int r = blockIdx.x * blockDim.x + threadIdx.x;
    if (r >= n) return;
    float d = rsqrtf(deg[r]);   // deg >= 1 always (self-loop)
    dinv[r] = d;
    float d2 = d * d;
    const float4* hi = (const float4*)(h1 + (size_t)r * F_HID);
    float4* ao = (float4*)(agg1 + (size_t)r * F_HID);
#pragma unroll
    for (int q = 0; q < 4; ++q) {
        float4 v = hi[q];
        ao[q] = make_float4(d2 * v.x, d2 * v.y, d2 * v.z, d2 * v.w);
    }
}

// ---------------- scatter layer 1: thread per (edge, col) ----------------
__global__ void k_scatter1(const int* __restrict__ src, const int* __restrict__ dst,
                           const float* __restrict__ dinv, const float* __restrict__ h1,
                           float* __restrict__ agg1, int E) {
    int idx = blockIdx.x * blockDim.x + threadIdx.x;
    if (idx >= E * F_HID) return;
    int e = idx >> 4;
    int c = idx & 15;
    int s = src[e];
    int d = dst[e];
    float f = dinv[s] * dinv[d];
    atomicAdd(&agg1[(size_t)d * F_HID + c], f * h1[(size_t)s * F_HID + c]);
}

// ---------------- relu + bias1 + GEMM2: h2 = relu(agg1+b1) @ W2 (stride 8) ----------------
__global__ void k_layer2(const float* __restrict__ agg1, const float* __restrict__ b1,
                         const float* __restrict__ W2, float* __restrict__ h2, int n) {
    int r = blockIdx.x * blockDim.x + threadIdx.x;
    if (r >= n) return;
    float z[F_HID];
    const float4* ai = (const float4*)(agg1 + (size_t)r * F_HID);
#pragma unroll
    for (int q = 0; q < 4; ++q) {
        float4 v = ai[q];
        z[q * 4 + 0] = fmaxf(v.x + b1[q * 4 + 0], 0.0f);
        z[q * 4 + 1] = fmaxf(v.y + b1[q * 4 + 1], 0.0f);
        z[q * 4 + 2] = fmaxf(v.z + b1[q * 4 + 2], 0.0f);
        z[q * 4 + 3] = fmaxf(v.w + b1[q * 4 + 3], 0.0f);
    }
    float h[F_OUT];
#pragma unroll
    for (int c = 0; c < F_OUT; ++c) h[c] = 0.0f;
#pragma unroll
    for (int k = 0; k < F_HID; ++k)
#pragma unroll
        for (int c = 0; c < F_OUT; ++c)
            h[c] = fmaf(z[k], W2[k * F_OUT + c], h[c]);
    float4* o = (float4*)(h2 + (size_t)r * 8);
    o[0] = make_float4(h[0], h[1], h[2], h[3]);
    o[1] = make_float4(h[4], h[5], h[6], 0.0f);
}

// ---------------- out init: b2 + self-loop term (zero-fills d_out region) ----------------
__global__ void k_outinit(const float* __restrict__ dinv, const float* __restrict__ h2,
                          const float* __restrict__ b2, float* __restrict__ out, int n) {
    int i = blockIdx.x * blockDim.x + threadIdx.x;
    if (i >= n * F_OUT) return;
    int r = (int)((unsigned)i / F_OUT);
    int c = i - r * F_OUT;
    float d = dinv[r];
    out[i] = b2[c] + d * d * h2[(size_t)r * 8 + c];
}

// ---------------- scatter layer 2: thread per (edge, col) with 8-pad ----------------
__global__ void k_scatter2(const int* __restrict__ src, const int* __restrict__ dst,
                           const float* __restrict__ dinv, const float* __restrict__ h2,
                           float* __restrict__ out, int E) {
    int idx = blockIdx.x * blockDim.x + threadIdx.x;
    if (idx >= E * 8) return;
    int e = idx >> 3;
    int c = idx & 7;
    if (c >= F_OUT) return;
    int s = src[e];
    int d = dst[e];
    float f = dinv[s] * dinv[d];
    atomicAdd(&out[(size_t)d * F_OUT + c], f * h2[(size_t)s * 8 + c]);
}

extern "C" void kernel_launch(void* const* d_in, const int* in_sizes, int n_in,
                              void* d_out, int out_size, void* d_ws, size_t ws_size,
                              hipStream_t stream) {
    const float* x  = (const float*)d_in[0];
    const int*   ei = (const int*)d_in[1];      // int64 in source but JAX x64 off -> int32
    const float* W1 = (const float*)d_in[2];
    const float* b1 = (const float*)d_in[3];
    const float* W2 = (const float*)d_in[4];
    const float* b2 = (const float*)d_in[5];
    float* out = (float*)d_out;

    const int n = in_sizes[0] / F_IN;       // 100000
    const int E = in_sizes[1] / 2;          // 3200000
    const int* src = ei;
    const int* dst = ei + E;

    // workspace layout (floats), offsets padded to 4-float alignment
    size_t Np = ((size_t)n + 3) & ~(size_t)3;
    float* ws   = (float*)d_ws;
    float* deg  = ws;                 // Np
    float* dinv = ws + Np;            // Np
    float* h1   = ws + 2 * Np;        // 16*Np
    float* agg1 = ws + 18 * Np;       // 16*Np
    float* h2   = ws + 34 * Np;       // 8*Np   (total 42*Np floats ~= 16.8 MB)

    const int B = 256;
    k_init_deg  <<<(n + B - 1) / B, B, 0, stream>>>(deg, n);
    k_deg       <<<(E + B - 1) / B, B, 0, stream>>>(dst, deg, E);
    k_gemm1     <<<(n + B - 1) / B, B, 0, stream>>>(x, W1, h1, n);
    k_dinv_self1<<<(n + B - 1) / B, B, 0, stream>>>(deg, dinv, h1, agg1, n);
    k_scatter1  <<<(E * F_HID + B - 1) / B, B, 0, stream>>>(src, dst, dinv, h1, agg1, E);
    k_layer2    <<<(n + B - 1) / B, B, 0, stream>>>(agg1, b1, W2, h2, n);
    k_outinit   <<<(n * F_OUT + B - 1) / B, B, 0, stream>>>(dinv, h2, b2, out, n);
    k_scatter2  <<<(E * 8 + B - 1) / B, B, 0, stream>>>(src, dst, dinv, h2, out, E);
}

// Round 2
// 867.736 us; speedup vs baseline: 1.0232x; 1.0232x over previous
//
#include <hip/hip_runtime.h>

#define F_IN 512
#define F_HID 16
#define F_OUT 7
#define SCAN_CHUNK 512

// ---------------- zero int array ----------------
__global__ void k_zero(int* __restrict__ p, int n) {
    int i = blockIdx.x * blockDim.x + threadIdx.x;
    if (i < n) p[i] = 0;
}

// ---------------- histogram of dst ----------------
__global__ void k_count(const int* __restrict__ dst, int* __restrict__ counts, int E) {
    int e = blockIdx.x * blockDim.x + threadIdx.x;
    if (e < E) atomicAdd(&counts[dst[e]], 1);
}

// ---------------- scan level A: per-chunk sums (chunk = 512 counts) ----------------
__global__ void k_chunk_sum(const int* __restrict__ counts, int* __restrict__ chunk_sums, int n) {
    __shared__ int sm[256];
    int b = blockIdx.x, t = threadIdx.x;
    int base = b * SCAN_CHUNK;
    int s = 0;
    int i0 = base + t, i1 = base + 256 + t;
    if (i0 < n) s += counts[i0];
    if (i1 < n) s += counts[i1];
    sm[t] = s;
    __syncthreads();
    for (int off = 128; off > 0; off >>= 1) {
        if (t < off) sm[t] += sm[t + off];
        __syncthreads();
    }
    if (t == 0) chunk_sums[b] = sm[0];
}

// ---------------- scan level B: exclusive scan of chunk sums (1 block, <=512 chunks) ----------------
__global__ void k_scan_chunks(const int* __restrict__ chunk_sums, int* __restrict__ chunk_off, int nchunk) {
    __shared__ int sm[512];
    int t = threadIdx.x;
    sm[t] = (t < nchunk) ? chunk_sums[t] : 0;
    __syncthreads();
    for (int off = 1; off < 512; off <<= 1) {
        int x = sm[t];
        if (t >= off) x += sm[t - off];
        __syncthreads();
        sm[t] = x;
        __syncthreads();
    }
    if (t < nchunk) chunk_off[t] = (t == 0) ? 0 : sm[t - 1];
}

// ---------------- scan level C: per-element exclusive offsets + dinv ----------------
__global__ void k_scan_block(const int* __restrict__ counts, const int* __restrict__ chunk_off,
                             int* __restrict__ row_start, float* __restrict__ dinv, int n) {
    __shared__ int sm[SCAN_CHUNK];
    int b = blockIdx.x, t = threadIdx.x;
    int i = b * SCAN_CHUNK + t;
    int v = (i < n) ? counts[i] : 0;
    sm[t] = v;
    __syncthreads();
    for (int off = 1; off < SCAN_CHUNK; off <<= 1) {
        int x = sm[t];
        if (t >= off) x += sm[t - off];
        __syncthreads();
        sm[t] = x;
        __syncthreads();
    }
    if (i < n) {
        row_start[i] = chunk_off[b] + sm[t] - v;          // exclusive prefix
        dinv[i] = rsqrtf((float)(v + 1));                  // deg incl. self-loop
    }
}

// ---------------- CSR fill: row_start doubles as cursor (post: row_start[d] = row end) ----
__global__ void k_fill(const int* __restrict__ src, const int* __restrict__ dst,
                       int* __restrict__ row_start, int* __restrict__ sorted_src, int E) {
    int e = blockIdx.x * blockDim.x + threadIdx.x;
    if (e >= E) return;
    int d = dst[e];
    int pos = atomicAdd(&row_start[d], 1);
    sorted_src[pos] = src[e];
}

// ---------------- GEMM1: h1s = dinv[r] * (x @ W1), one row per thread ----------------
__global__ void k_gemm1(const float* __restrict__ x, const float* __restrict__ W,
                        const float* __restrict__ dinv, float* __restrict__ h1s, int n) {
    int r = blockIdx.x * blockDim.x + threadIdx.x;
    if (r >= n) return;
    float acc[F_HID];
#pragma unroll
    for (int c = 0; c < F_HID; ++c) acc[c] = 0.0f;
    const float4* xr = (const float4*)(x + (size_t)r * F_IN);
    for (int k4 = 0; k4 < F_IN / 4; ++k4) {
        float4 xv = xr[k4];
        int k = k4 * 4;
#pragma unroll
        for (int c = 0; c < F_HID; ++c) {
            acc[c] = fmaf(xv.x, W[(k + 0) * F_HID + c], acc[c]);
            acc[c] = fmaf(xv.y, W[(k + 1) * F_HID + c], acc[c]);
            acc[c] = fmaf(xv.z, W[(k + 2) * F_HID + c], acc[c]);
            acc[c] = fmaf(xv.w, W[(k + 3) * F_HID + c], acc[c]);
        }
    }
    float dv = dinv[r];
    float4* o = (float4*)(h1s + (size_t)r * F_HID);
    o[0] = make_float4(dv * acc[0], dv * acc[1], dv * acc[2], dv * acc[3]);
    o[1] = make_float4(dv * acc[4], dv * acc[5], dv * acc[6], dv * acc[7]);
    o[2] = make_float4(dv * acc[8], dv * acc[9], dv * acc[10], dv * acc[11]);
    o[3] = make_float4(dv * acc[12], dv * acc[13], dv * acc[14], dv * acc[15]);
}

// ---------------- aggregation layer 1: 16 lanes per node, gather + register sum -------
__global__ void k_agg1(const int* __restrict__ row_start, const int* __restrict__ sorted_src,
                       const float* __restrict__ h1s, const float* __restrict__ dinv,
                       float* __restrict__ agg1, int n) {
    int t = blockIdx.x * blockDim.x + threadIdx.x;
    int d = t >> 4;
    int c = t & 15;
    if (d >= n) return;
    int start = (d == 0) ? 0 : row_start[d - 1];   // post-fill: row_start[d] = end of row d
    int end = row_start[d];
    float acc = h1s[(size_t)d * F_HID + c];        // self-loop term (pre-scaled by dinv[d])
    for (int j = start; j < end; ++j) {
        int s = sorted_src[j];
        acc += h1s[(size_t)s * F_HID + c];
    }
    agg1[(size_t)d * F_HID + c] = dinv[d] * acc;
}

// ---------------- relu+bias1+GEMM2, store h2s = dinv * h2 (stride 8, col7 = 0) --------
__global__ void k_layer2(const float* __restrict__ agg1, const float* __restrict__ b1,
                         const float* __restrict__ W2, const float* __restrict__ dinv,
                         float* __restrict__ h2s, int n) {
    int r = blockIdx.x * blockDim.x + threadIdx.x;
    if (r >= n) return;
    float z[F_HID];
    const float4* ai = (const float4*)(agg1 + (size_t)r * F_HID);
#pragma unroll
    for (int q = 0; q < 4; ++q) {
        float4 v = ai[q];
        z[q * 4 + 0] = fmaxf(v.x + b1[q * 4 + 0], 0.0f);
        z[q * 4 + 1] = fmaxf(v.y + b1[q * 4 + 1], 0.0f);
        z[q * 4 + 2] = fmaxf(v.z + b1[q * 4 + 2], 0.0f);
        z[q * 4 + 3] = fmaxf(v.w + b1[q * 4 + 3], 0.0f);
    }
    float h[F_OUT];
#pragma unroll
    for (int c = 0; c < F_OUT; ++c) h[c] = 0.0f;
#pragma unroll
    for (int k = 0; k < F_HID; ++k)
#pragma unroll
        for (int c = 0; c < F_OUT; ++c)
            h[c] = fmaf(z[k], W2[k * F_OUT + c], h[c]);
    float dv = dinv[r];
    float4* o = (float4*)(h2s + (size_t)r * 8);
    o[0] = make_float4(dv * h[0], dv * h[1], dv * h[2], dv * h[3]);
    o[1] = make_float4(dv * h[4], dv * h[5], dv * h[6], 0.0f);
}

// ---------------- aggregation layer 2: 8 lanes per node, writes final out -------------
__global__ void k_agg2(const int* __restrict__ row_start, const int* __restrict__ sorted_src,
                       const float* __restrict__ h2s, const float* __restrict__ dinv,
                       const float* __restrict__ b2, float* __restrict__ out, int n) {
    int t = blockIdx.x * blockDim.x + threadIdx.x;
    int d = t >> 3;
    int c = t & 7;
    if (d >= n) return;
    int start = (d == 0) ? 0 : row_start[d - 1];
    int end = row_start[d];
    float acc = h2s[(size_t)d * 8 + c];            // self-loop (col 7 is 0)
    for (int j = start; j < end; ++j) {
        int s = sorted_src[j];
        acc += h2s[(size_t)s * 8 + c];
    }
    if (c < F_OUT)
        out[(size_t)d * F_OUT + c] = dinv[d] * acc + b2[c];
}

extern "C" void kernel_launch(void* const* d_in, const int* in_sizes, int n_in,
                              void* d_out, int out_size, void* d_ws, size_t ws_size,
                              hipStream_t stream) {
    const float* x  = (const float*)d_in[0];
    const int*   ei = (const int*)d_in[1];      // int64 in source but JAX x64 off -> int32
    const float* W1 = (const float*)d_in[2];
    const float* b1 = (const float*)d_in[3];
    const float* W2 = (const float*)d_in[4];
    const float* b2 = (const float*)d_in[5];
    float* out = (float*)d_out;

    const int n = in_sizes[0] / F_IN;       // 100000
    const int E = in_sizes[1] / 2;          // 3200000
    const int* src = ei;
    const int* dst = ei + E;

    // workspace layout (4-byte units, 16B-aligned sections)
    size_t Np = ((size_t)n + 3) & ~(size_t)3;
    size_t Ep = ((size_t)E + 3) & ~(size_t)3;
    char* ws = (char*)d_ws;
    int*   counts     = (int*)ws;                       ws += Np * 4;
    int*   row_start  = (int*)ws;                       ws += Np * 4;
    int*   chunk_sums = (int*)ws;                       ws += 512 * 4;
    int*   chunk_off  = (int*)ws;                       ws += 512 * 4;
    float* dinv       = (float*)ws;                     ws += Np * 4;
    int*   sorted_src = (int*)ws;                       ws += Ep * 4;
    float* h1s        = (float*)ws;                     ws += Np * F_HID * 4;
    float* agg1       = (float*)ws;                     ws += Np * F_HID * 4;
    float* h2s        = h1s;                            // h1s dead after k_agg1

    const int B = 256;
    const int nchunk = (n + SCAN_CHUNK - 1) / SCAN_CHUNK;   // 196 for n=100000 (<=512 req)

    k_zero      <<<(n + B - 1) / B, B, 0, stream>>>(counts, n);
    k_count     <<<(E + B - 1) / B, B, 0, stream>>>(dst, counts, E);
    k_chunk_sum <<<nchunk, 256, 0, stream>>>(counts, chunk_sums, n);
    k_scan_chunks<<<1, 512, 0, stream>>>(chunk_sums, chunk_off, nchunk);
    k_scan_block<<<nchunk, SCAN_CHUNK, 0, stream>>>(counts, chunk_off, row_start, dinv, n);
    k_gemm1     <<<(n + B - 1) / B, B, 0, stream>>>(x, W1, dinv, h1s, n);
    k_fill      <<<(E + B - 1) / B, B, 0, stream>>>(src, dst, row_start, sorted_src, E);
    k_agg1      <<<((size_t)n * F_HID + B - 1) / B, B, 0, stream>>>(row_start, sorted_src, h1s, dinv, agg1, n);
    k_layer2    <<<(n + B - 1) / B, B, 0, stream>>>(agg1, b1, W2, dinv, h2s, n);
    k_agg2      <<<((size_t)n * 8 + B - 1) / B, B, 0, stream>>>(row_start, sorted_src, h2s, dinv, b2, out, n);
}